// Round 4
// baseline (160.522 us; speedup 1.0000x reference)
//
#include <hip/hip_runtime.h>
#include <hip/hip_bf16.h>

typedef unsigned short u16;
typedef __attribute__((ext_vector_type(8))) short short8;
typedef __attribute__((ext_vector_type(4))) float f32x4;
typedef __attribute__((ext_vector_type(4))) float float4v;
typedef __attribute__((ext_vector_type(4))) unsigned int uint4v;

__device__ __forceinline__ u16 f2bf(float f) {
    union { float f; unsigned u; } x;
    x.f = f;
    unsigned r = x.u + 0x7fffu + ((x.u >> 16) & 1u);  // RNE
    return (u16)(r >> 16);
}
__device__ __forceinline__ u16 f2bf_fast(float f) {   // round-half-up (p >= 0)
    unsigned u = __builtin_bit_cast(unsigned, f);
    return (u16)((u + 0x8000u) >> 16);
}

__device__ __forceinline__ void gload16(const u16* g, u16* l) {
    __builtin_amdgcn_global_load_lds(
        (const __attribute__((address_space(1))) unsigned*)g,
        (__attribute__((address_space(3))) unsigned*)l, 16, 0, 0);
}

// DPP 16-lane-row sum reduce (4 VALU-rate steps, no LDS traffic)
#define DPP_F(x, ctrl) __builtin_bit_cast(float, __builtin_amdgcn_update_dpp( \
    0, __builtin_bit_cast(int, (x)), (ctrl), 0xF, 0xF, true))
__device__ __forceinline__ float rowsum16(float x) {
    x += DPP_F(x, 0xB1);   // quad_perm xor1
    x += DPP_F(x, 0x4E);   // quad_perm xor2
    x += DPP_F(x, 0x124);  // row_ror:4
    x += DPP_F(x, 0x128);  // row_ror:8
    return x;
}

// ---------------- cast x (fp32) -> bf16, 8 elems/thread ----------------
__global__ __launch_bounds__(256) void cast_f32_bf16(
    const float* __restrict__ src, u16* __restrict__ dst, int n8) {
    int i = blockIdx.x * 256 + threadIdx.x;
    if (i >= n8) return;
    const float4v* s = (const float4v*)(src + (size_t)i * 8);
    float4v a = s[0], b = s[1];
    uint4v o;
    o[0] = (unsigned)f2bf(a[0]) | ((unsigned)f2bf(a[1]) << 16);
    o[1] = (unsigned)f2bf(a[2]) | ((unsigned)f2bf(a[3]) << 16);
    o[2] = (unsigned)f2bf(b[0]) | ((unsigned)f2bf(b[1]) << 16);
    o[3] = (unsigned)f2bf(b[2]) | ((unsigned)f2bf(b[3]) << 16);
    *(uint4v*)(dst + (size_t)i * 8) = o;
}

// ---------------- transpose fp32 [R][C] -> bf16 [C][R] ----------------
__global__ __launch_bounds__(256) void transpose_f32_bf16(
    const float* __restrict__ src, u16* __restrict__ dst, int R, int C) {
    __shared__ __align__(16) u16 tile[64][72];
    int tr = blockIdx.x * 64;
    int tc = blockIdx.y * 64;
    int t = threadIdx.x;
    int r = t >> 2;
    int c4 = (t & 3) * 16;
    const float4v* sp = (const float4v*)(src + (size_t)(tr + r) * C + tc + c4);
#pragma unroll
    for (int v = 0; v < 4; v++) {
        float4v x = sp[v];
#pragma unroll
        for (int j = 0; j < 4; j++) tile[r][c4 + v * 4 + j] = f2bf(x[j]);
    }
    __syncthreads();
    u16* dp = dst + (size_t)(tc + r) * R + tr + c4;
#pragma unroll
    for (int i = 0; i < 16; i++) dp[i] = tile[c4 + i][r];
}

// ---------------- build Vt[bh][d=64][s=2048] from qkv bf16 ----------------
__global__ __launch_bounds__(256) void build_vt(
    const u16* __restrict__ qkv, u16* __restrict__ vt) {
    int bh = blockIdx.y;
    int b = bh >> 4, h = bh & 15;
    int sbase = blockIdx.x * 64;
    __shared__ __align__(16) u16 tile[64][72];
    int t = threadIdx.x;
    int r = t >> 2;
    int c4 = (t & 3) * 16;
    const u16* sp = qkv + (size_t)(b * 2048 + sbase + r) * 3072 + 2048 + h * 64 + c4;
    *(uint4v*)&tile[r][c4] = *(const uint4v*)sp;
    *(uint4v*)&tile[r][c4 + 8] = *(const uint4v*)(sp + 8);
    __syncthreads();
    u16* dp = vt + (size_t)bh * 64 * 2048 + (size_t)r * 2048 + sbase + c4;
#pragma unroll
    for (int i = 0; i < 16; i++) dp[i] = tile[c4 + i][r];
}

// ---------------- bf16 MFMA GEMM (m97-style global_load_lds staging) -------
template <bool OUT_BF16>
__global__ __launch_bounds__(256) void gemm_kernel(
    const u16* __restrict__ A, const u16* __restrict__ BT,
    const float* __restrict__ bias, void* __restrict__ Cout,
    int M, int N, int K) {
    __shared__ __align__(16) u16 As[128 * 32];
    __shared__ __align__(16) u16 Bs[128 * 32];
    // bijective XCD swizzle: consecutive-8 round-robin -> contiguous chunks/XCD
    int nwg = gridDim.x * gridDim.y;
    int lin = blockIdx.y * gridDim.x + blockIdx.x;
    int swz = (lin & 7) * (nwg >> 3) + (lin >> 3);
    int bm = swz % gridDim.x;
    int bn = swz / gridDim.x;
    int t = threadIdx.x;
    int lane = t & 63, wave = t >> 6;
    int wr = wave >> 1, wc = wave & 1;
    f32x4 acc[4][4] = {};

    int lrow = lane >> 2;
    int lk = (lane & 3) * 8;
    const u16* gA = A + (size_t)(bm * 128) * K;
    const u16* gB = BT + (size_t)(bn * 128) * K;

    for (int k0 = 0; k0 < K; k0 += 32) {
        __syncthreads();
#pragma unroll
        for (int i = 0; i < 2; i++) {
            int ch = wave * 2 + i;
            int row = ch * 16 + lrow;
            gload16(gA + (size_t)row * K + k0 + lk, &As[ch * 16 * 32]);
            gload16(gB + (size_t)row * K + k0 + lk, &Bs[ch * 16 * 32]);
        }
        __syncthreads();
        int row16 = lane & 15, kg = (lane >> 4) * 8;
        short8 af[4], bf[4];
#pragma unroll
        for (int m = 0; m < 4; m++)
            af[m] = *(const short8*)&As[(wr * 64 + m * 16 + row16) * 32 + kg];
#pragma unroll
        for (int n = 0; n < 4; n++)
            bf[n] = *(const short8*)&Bs[(wc * 64 + n * 16 + row16) * 32 + kg];
#pragma unroll
        for (int m = 0; m < 4; m++)
#pragma unroll
            for (int n = 0; n < 4; n++)
                acc[m][n] = __builtin_amdgcn_mfma_f32_16x16x32_bf16(
                    af[m], bf[n], acc[m][n], 0, 0, 0);
    }

#pragma unroll
    for (int m = 0; m < 4; m++) {
#pragma unroll
        for (int n = 0; n < 4; n++) {
            int col = bn * 128 + wc * 64 + n * 16 + (lane & 15);
            float bv = bias ? bias[col] : 0.f;
#pragma unroll
            for (int r = 0; r < 4; r++) {
                int row = bm * 128 + wr * 64 + m * 16 + (lane >> 4) * 4 + r;
                float v = acc[m][n][r] + bv;
                if constexpr (OUT_BF16)
                    ((u16*)Cout)[(size_t)row * N + col] = f2bf(v);
                else
                    ((float*)Cout)[(size_t)row * N + col] = v;
            }
        }
    }
}

// ---------------- causal flash attention v4 ------------------------------
// One wave per block (2048 blocks, all co-resident: 8 waves/CU). No barriers.
// K/V fragments register double-buffered from global (L2-resident per XCD).
// Softmax: p = exp2(s*0.125/ln2 - 12/ln2) -- static offset, no rescale, one
// DPP row-reduce at the end. P transposed through per-wave LDS.
__global__ __launch_bounds__(64, 2) void attn_kernel(
    const u16* __restrict__ qkv, const u16* __restrict__ vt,
    u16* __restrict__ attn) {
    int bid = blockIdx.x;
    int bh = bid & 31;                 // fast dim -> XCD pinning (4 heads/XCD)
    int i = bid >> 5;                  // 0..63 stripe slot
    int mm = i >> 3, rr = i & 7;
    int s = mm * 8 + ((mm & 1) ? 7 - rr : rr);   // per-CU balanced permutation
    int qb = 2016 - s * 32;            // heavy stripes first
    int b = bh >> 4, h = bh & 15;
    int lane = threadIdx.x;
    int r15 = lane & 15, hi = lane >> 4, hi4 = hi << 2;

    __shared__ __align__(16) u16 pl[32][72];

    const u16* qbase = qkv + (size_t)(b * 2048) * 3072 + h * 64;
    const u16* kb_l = qkv + (size_t)(b * 2048) * 3072 + 1024 + h * 64 + r15 * 3072 + hi * 8;
    const u16* vb_l = vt + (size_t)bh * 131072 + r15 * 2048 + hi * 8;

    // Q fragments (raw bf16; 1/8 scale folded into exp2 constant)
    short8 qf[2][2];
#pragma unroll
    for (int h2 = 0; h2 < 2; h2++) {
        const u16* q0 = qbase + (size_t)(qb + h2 * 16 + r15) * 3072 + hi * 8;
        qf[h2][0] = *(const short8*)q0;
        qf[h2][1] = *(const short8*)(q0 + 32);
    }

    float l_lane[2][4] = {};
    f32x4 o[2][4];
#pragma unroll
    for (int h2 = 0; h2 < 2; h2++)
#pragma unroll
        for (int nb = 0; nb < 4; nb++) o[h2][nb] = (f32x4){0.f, 0.f, 0.f, 0.f};

    auto loadt = [&](int tt, short8(&kf)[4][2], short8(&vf)[4][2]) {
        const u16* kp = kb_l + (size_t)tt * 196608;   // 64 rows * 3072
        const u16* vp = vb_l + tt * 64;
#pragma unroll
        for (int kt = 0; kt < 4; kt++)
#pragma unroll
            for (int g = 0; g < 2; g++)
                kf[kt][g] = *(const short8*)(kp + kt * 49152 + g * 32);
#pragma unroll
        for (int nb = 0; nb < 4; nb++)
#pragma unroll
            for (int g = 0; g < 2; g++)
                vf[nb][g] = *(const short8*)(vp + nb * 32768 + g * 32);
    };

    const float C1 = 0.1803368880f;    // 0.125/ln2
    const float C2 = -17.3123404907f;  // 12/ln2

    auto compute = [&](const short8(&kf)[4][2], const short8(&vf)[4][2], int k0) {
        f32x4 sc[2][4];
        __builtin_amdgcn_s_setprio(1);
#pragma unroll
        for (int h2 = 0; h2 < 2; h2++)
#pragma unroll
            for (int kt = 0; kt < 4; kt++) {
                f32x4 z = (f32x4){0.f, 0.f, 0.f, 0.f};
                z = __builtin_amdgcn_mfma_f32_16x16x32_bf16(qf[h2][0], kf[kt][0], z, 0, 0, 0);
                sc[h2][kt] = __builtin_amdgcn_mfma_f32_16x16x32_bf16(qf[h2][1], kf[kt][1], z, 0, 0, 0);
            }
        __builtin_amdgcn_s_setprio(0);
        bool diag = (k0 + 64 > qb);
#pragma unroll
        for (int h2 = 0; h2 < 2; h2++)
#pragma unroll
            for (int r = 0; r < 4; r++) {
                int q = qb + h2 * 16 + hi4 + r;
                float pv4[4];
#pragma unroll
                for (int kt = 0; kt < 4; kt++) {
                    float v = sc[h2][kt][r];
                    if (diag && (k0 + kt * 16 + r15 > q)) v = -1e30f;
                    pv4[kt] = __builtin_amdgcn_exp2f(fmaf(v, C1, C2));
                }
                l_lane[h2][r] += (pv4[0] + pv4[1]) + (pv4[2] + pv4[3]);
                int prow = h2 * 16 + hi4 + r;
#pragma unroll
                for (int kt = 0; kt < 4; kt++)
                    pl[prow][kt * 16 + r15] = f2bf_fast(pv4[kt]);
            }
        short8 pf[2][2];
#pragma unroll
        for (int h2 = 0; h2 < 2; h2++)
#pragma unroll
            for (int g2 = 0; g2 < 2; g2++)
                pf[h2][g2] = *(const short8*)&pl[h2 * 16 + r15][g2 * 32 + hi * 8];
        __builtin_amdgcn_s_setprio(1);
#pragma unroll
        for (int nb = 0; nb < 4; nb++)
#pragma unroll
            for (int g2 = 0; g2 < 2; g2++) {
                o[0][nb] = __builtin_amdgcn_mfma_f32_16x16x32_bf16(pf[0][g2], vf[nb][g2], o[0][nb], 0, 0, 0);
                o[1][nb] = __builtin_amdgcn_mfma_f32_16x16x32_bf16(pf[1][g2], vf[nb][g2], o[1][nb], 0, 0, 0);
            }
        __builtin_amdgcn_s_setprio(0);
    };

    int nt = (qb + 95) >> 6;           // ceil((qb+32)/64)
    short8 kA[4][2], vA[4][2], kB[4][2], vB[4][2];
    loadt(0, kA, vA);
    for (int t = 0; t < nt; t += 2) {
        if (t + 1 < nt) loadt(t + 1, kB, vB);
        compute(kA, vA, t * 64);
        if (t + 1 < nt) {
            if (t + 2 < nt) loadt(t + 2, kA, vA);
            compute(kB, vB, (t + 1) * 64);
        }
    }

    // ---- finalize: one cross-lane reduce of l per row, then normalize ----
    float linv[2][4];
#pragma unroll
    for (int h2 = 0; h2 < 2; h2++)
#pragma unroll
        for (int r = 0; r < 4; r++)
            linv[h2][r] = __builtin_amdgcn_rcpf(rowsum16(l_lane[h2][r]));
#pragma unroll
    for (int h2 = 0; h2 < 2; h2++)
#pragma unroll
        for (int nb = 0; nb < 4; nb++)
#pragma unroll
            for (int r = 0; r < 4; r++) {
                int q = qb + h2 * 16 + hi4 + r;
                attn[(size_t)(b * 2048 + q) * 1024 + h * 64 + nb * 16 + r15] =
                    f2bf(o[h2][nb][r] * linv[h2][r]);
            }
}

extern "C" void kernel_launch(void* const* d_in, const int* in_sizes, int n_in,
                              void* d_out, int out_size, void* d_ws, size_t ws_size,
                              hipStream_t stream) {
    const float* x    = (const float*)d_in[0];
    const float* Wqkv = (const float*)d_in[1];
    const float* bqkv = (const float*)d_in[2];
    const float* Wo   = (const float*)d_in[3];
    const float* bo   = (const float*)d_in[4];
    float* out = (float*)d_out;

    char* ws = (char*)d_ws;
    u16* x_bf  = (u16*)(ws);                    //  8 MB: [4096][1024]
    u16* wqkvT = (u16*)(ws + (8ull << 20));     //  6 MB: [3072][1024]
    u16* woT   = (u16*)(ws + (14ull << 20));    //  2 MB: [1024][1024]
    u16* qkv   = (u16*)(ws + (16ull << 20));    // 24 MB: [4096][3072]
    u16* vt    = (u16*)(ws + (40ull << 20));    //  8 MB: [32][64][2048]
    u16* attnb = (u16*)(ws + (48ull << 20));    //  8 MB: [4096][1024]

    cast_f32_bf16<<<2048, 256, 0, stream>>>(x, x_bf, 4096 * 1024 / 8);
    transpose_f32_bf16<<<dim3(16, 48), 256, 0, stream>>>(Wqkv, wqkvT, 1024, 3072);
    transpose_f32_bf16<<<dim3(16, 16), 256, 0, stream>>>(Wo, woT, 1024, 1024);
    gemm_kernel<true><<<dim3(32, 24), 256, 0, stream>>>(
        x_bf, wqkvT, bqkv, (void*)qkv, 4096, 3072, 1024);
    build_vt<<<dim3(32, 32), 256, 0, stream>>>(qkv, vt);
    attn_kernel<<<2048, 64, 0, stream>>>(qkv, vt, attnb);
    gemm_kernel<false><<<dim3(32, 8), 256, 0, stream>>>(
        attnb, woT, bo, (void*)out, 4096, 1024, 1024);
}